// Round 3
// baseline (5006.102 us; speedup 1.0000x reference)
//
#include <hip/hip_runtime.h>

typedef unsigned int u32;
typedef _Float16 half_t;
typedef _Float16 half2_t __attribute__((ext_vector_type(2)));

#define B_ 64
#define T_ 2048
#define I_ 128
#define H_ 512
#define O_ 128

static __device__ __forceinline__ float dot2w(u32 w, u32 h, float acc) {
  return __builtin_amdgcn_fdot2(__builtin_bit_cast(half2_t, w),
                                __builtin_bit_cast(half2_t, h), acc, false);
}

// ---------------- K1: pack masked weights to fp16 layouts ----------------
// Whh_pk layout: word q (=j*32+m) of lane l stored at [ (q/4)*2048 + l*4 + (q&3) ]
//   lane l owns rows r_j = (l>>3)*8 + j (j=0..7), k-range [ (l&7)*64, +64 )
__global__ void k_prep(const float* __restrict__ Whh, const float* __restrict__ Mhh,
                       const float* __restrict__ Wih, const float* __restrict__ Mih,
                       const float* __restrict__ Wfc,
                       u32* __restrict__ Whh_pk, u32* __restrict__ Wih_pk,
                       u32* __restrict__ Wfc_pk) {
  int idx = blockIdx.x * 256 + threadIdx.x;
  if (idx < 512 * 256) {
    int w4 = idx >> 11;
    int rem = idx & 2047;
    int l = rem >> 2;
    int c = rem & 3;
    int q = w4 * 4 + c;
    int j = q >> 5;
    int m = q & 31;
    int row = (l >> 3) * 8 + j;
    int k0 = (l & 7) * 64 + m * 2;
    float a = Whh[row * 512 + k0]     * Mhh[row * 512 + k0];
    float b = Whh[row * 512 + k0 + 1] * Mhh[row * 512 + k0 + 1];
    half2_t hv = { (half_t)a, (half_t)b };
    Whh_pk[idx] = __builtin_bit_cast(u32, hv);
  } else if (idx < 512 * 256 + 512 * 64) {
    int i2 = idx - 512 * 256;
    int h = i2 >> 6, w = i2 & 63;
    int k0 = w * 2;
    float a = Wih[h * 128 + k0]     * Mih[h * 128 + k0];
    float b = Wih[h * 128 + k0 + 1] * Mih[h * 128 + k0 + 1];
    half2_t hv = { (half_t)a, (half_t)b };
    Wih_pk[h * 64 + w] = __builtin_bit_cast(u32, hv);
  } else if (idx < 512 * 256 + 512 * 64 + 128 * 256) {
    int i3 = idx - (512 * 256 + 512 * 64);
    int o = i3 >> 8, w = i3 & 255;
    float a = Wfc[o * 512 + 2 * w];
    float b = Wfc[o * 512 + 2 * w + 1];
    half2_t hv = { (half_t)a, (half_t)b };
    Wfc_pk[o * 256 + w] = __builtin_bit_cast(u32, hv);
  }
}

// ---------------- K2: xproj[b][t][h] = x . Wih_m^T + b_ih + b_hh (fp16 out) ----
__launch_bounds__(512, 2)
__global__ void k_xproj(const float* __restrict__ x, const u32* __restrict__ Wih_pk,
                        const float* __restrict__ b_ih, const float* __restrict__ b_hh,
                        half_t* __restrict__ xp) {
  const int l = threadIdx.x;           // l = h
  const int r0 = blockIdx.x * 256;     // 256 (b,t) rows per block
  __shared__ u32 xb[2][64];
  u32 W[64];
#pragma unroll
  for (int i = 0; i < 16; ++i)
    *(uint4*)&W[i * 4] = *(const uint4*)(Wih_pk + l * 64 + i * 4);
  const float bs = b_ih[l] + b_hh[l];

  float2 g = { 0.f, 0.f };
  if (l < 64) {
    g = *(const float2*)(x + (size_t)r0 * 128 + 2 * l);
    half2_t hv = { (half_t)g.x, (half_t)g.y };
    xb[0][l] = __builtin_bit_cast(u32, hv);
    g = *(const float2*)(x + (size_t)(r0 + 1) * 128 + 2 * l);
  }
  __syncthreads();
  for (int i = 0; i < 256; ++i) {
    if (l < 64 && i + 1 < 256) {
      half2_t hv = { (half_t)g.x, (half_t)g.y };
      xb[(i + 1) & 1][l] = __builtin_bit_cast(u32, hv);
      int nf = (i + 2 < 256) ? i + 2 : i + 1;
      g = *(const float2*)(x + (size_t)(r0 + nf) * 128 + 2 * l);
    }
    float a0 = 0.f, a1 = 0.f;
#pragma unroll
    for (int m = 0; m < 16; ++m) {
      uint4 hv = *(const uint4*)&xb[i & 1][m * 4];
      a0 = dot2w(W[m * 4 + 0], hv.x, a0);
      a1 = dot2w(W[m * 4 + 1], hv.y, a1);
      a0 = dot2w(W[m * 4 + 2], hv.z, a0);
      a1 = dot2w(W[m * 4 + 3], hv.w, a1);
    }
    xp[(size_t)(r0 + i) * 512 + l] = (half_t)(a0 + a1 + bs);
    __syncthreads();
  }
}

// ---------------- K3: recurrence, one block per batch element ----------------
// hs aliases xp (read-before-write per t with 2-deep prefetch; disjoint b per block).
// Weights: 160 u32/lane in VGPRs (m4 0..4); m4 5..7 re-streamed from L2 every
// step (identical across blocks -> resident in every XCD L2). Pointer-launder
// asm prevents hoisting of the invariant loads/addresses out of the t-loop.
__launch_bounds__(512, 1)
__global__ void k_rec(const u32* __restrict__ Whh_pk, half_t* __restrict__ xp,
                      const float* __restrict__ h0) {
  const int b = blockIdx.x;
  const int l = threadIdx.x;
  const int g = l & 7;                  // k-group: k in [g*64, g*64+64)

  __shared__ u32 hbuf[2][288];          // h fp16 packed; 32-word chunks padded +4

  // register-resident weights: m4 groups 0..4 -> W[j*20 + m4*4 + i]
  u32 W[160];
#pragma unroll
  for (int j = 0; j < 8; ++j)
#pragma unroll
    for (int m4 = 0; m4 < 5; ++m4) {
      uint4 v = *(const uint4*)(Whh_pk + (size_t)(j * 8 + m4) * 2048 + l * 4);
      W[j * 20 + m4 * 4 + 0] = v.x; W[j * 20 + m4 * 4 + 1] = v.y;
      W[j * 20 + m4 * 4 + 2] = v.z; W[j * 20 + m4 * 4 + 3] = v.w;
    }

  // initial h from h0 (padded-chunk layout: word w goes to w + (w/32)*4)
  if (l < 256) {
    float2 hv = *(const float2*)(h0 + (size_t)b * 512 + 2 * l);
    half2_t hh = { (half_t)hv.x, (half_t)hv.y };
    hbuf[0][l + (l >> 5) * 4] = __builtin_bit_cast(u32, hh);
  }
  __syncthreads();

  const uint4* wstream = (const uint4*)Whh_pk + l;   // element (j*8+m4)*512

  half_t* xpb = xp + (size_t)b * T_ * 512 + l;       // row == l
  half_t xp0 = xpb[0];
  half_t xp1 = xpb[512];

  const int b0 = l & 1, b1 = (l >> 1) & 1, b2 = (l >> 2) & 1;
  const int hwIdx = (l >> 1) + (l >> 6) * 4;         // padded word idx of row's halfword
  int cur = 0;

  for (int t = 0; t < T_; ++t) {
    // ---- issue streamed batch m4=5 (latency hides under m4 0..4 compute) ----
    const uint4* p5 = wstream;
    asm volatile("" : "+v"(p5));
    uint4 L5[8];
#pragma unroll
    for (int j = 0; j < 8; ++j) L5[j] = p5[(j * 8 + 5) * 512];

    int tpf = (t + 2 < T_) ? t + 2 : T_ - 1;
    half_t xpn = xpb[(size_t)tpf * 512];             // xp prefetch, 2 steps ahead

    float acc[8];
#pragma unroll
    for (int j = 0; j < 8; ++j) acc[j] = 0.f;

    // ---- m4 = 0..4 from registers ----
#pragma unroll
    for (int m4 = 0; m4 < 5; ++m4) {
      uint4 hh = *(const uint4*)&hbuf[cur][g * 36 + m4 * 4];
#pragma unroll
      for (int j = 0; j < 8; ++j) {
        acc[j] = dot2w(W[j * 20 + m4 * 4 + 0], hh.x, acc[j]);
        acc[j] = dot2w(W[j * 20 + m4 * 4 + 1], hh.y, acc[j]);
        acc[j] = dot2w(W[j * 20 + m4 * 4 + 2], hh.z, acc[j]);
        acc[j] = dot2w(W[j * 20 + m4 * 4 + 3], hh.w, acc[j]);
      }
    }

    // ---- issue batch m4=6, then consume L5 ----
    __builtin_amdgcn_sched_barrier(0);
    const uint4* p6 = wstream;
    asm volatile("" : "+v"(p6));
    uint4 L6[8];
#pragma unroll
    for (int j = 0; j < 8; ++j) L6[j] = p6[(j * 8 + 6) * 512];
    {
      uint4 hh = *(const uint4*)&hbuf[cur][g * 36 + 20];
#pragma unroll
      for (int j = 0; j < 8; ++j) {
        acc[j] = dot2w(L5[j].x, hh.x, acc[j]);
        acc[j] = dot2w(L5[j].y, hh.y, acc[j]);
        acc[j] = dot2w(L5[j].z, hh.z, acc[j]);
        acc[j] = dot2w(L5[j].w, hh.w, acc[j]);
      }
    }

    // ---- issue batch m4=7, then consume L6 ----
    __builtin_amdgcn_sched_barrier(0);
    const uint4* p7 = wstream;
    asm volatile("" : "+v"(p7));
    uint4 L7[8];
#pragma unroll
    for (int j = 0; j < 8; ++j) L7[j] = p7[(j * 8 + 7) * 512];
    {
      uint4 hh = *(const uint4*)&hbuf[cur][g * 36 + 24];
#pragma unroll
      for (int j = 0; j < 8; ++j) {
        acc[j] = dot2w(L6[j].x, hh.x, acc[j]);
        acc[j] = dot2w(L6[j].y, hh.y, acc[j]);
        acc[j] = dot2w(L6[j].z, hh.z, acc[j]);
        acc[j] = dot2w(L6[j].w, hh.w, acc[j]);
      }
    }
    {
      uint4 hh = *(const uint4*)&hbuf[cur][g * 36 + 28];
#pragma unroll
      for (int j = 0; j < 8; ++j) {
        acc[j] = dot2w(L7[j].x, hh.x, acc[j]);
        acc[j] = dot2w(L7[j].y, hh.y, acc[j]);
        acc[j] = dot2w(L7[j].z, hh.z, acc[j]);
        acc[j] = dot2w(L7[j].w, hh.w, acc[j]);
      }
    }

    // keep-half butterfly over the 8-lane k-group dim; lane l ends with row l total
    float s4[4];
#pragma unroll
    for (int m = 0; m < 4; ++m) {
      float keep = b0 ? acc[2 * m + 1] : acc[2 * m];
      float send = b0 ? acc[2 * m]     : acc[2 * m + 1];
      s4[m] = keep + __shfl_xor(send, 1, 64);
    }
    float s2[2];
#pragma unroll
    for (int m = 0; m < 2; ++m) {
      float keep = b1 ? s4[2 * m + 1] : s4[2 * m];
      float send = b1 ? s4[2 * m]     : s4[2 * m + 1];
      s2[m] = keep + __shfl_xor(send, 2, 64);
    }
    float keepf = b2 ? s2[1] : s2[0];
    float sendf = b2 ? s2[0] : s2[1];
    float tot = keepf + __shfl_xor(sendf, 4, 64);

    float sarg = tot + (float)xp0;
    float ax = fabsf(sarg);
    float e = __expf(-2.f * ax);
    float r = (1.f - e) * __builtin_amdgcn_rcpf(1.f + e);
    float hval = copysignf(r, sarg);

    half_t hv = (half_t)hval;
    ((half_t*)hbuf[cur ^ 1])[hwIdx * 2 + (l & 1)] = hv;
    xpb[(size_t)t * 512] = hv;            // overwrite consumed xproj slot with h

    xp0 = xp1; xp1 = xpn;
    __syncthreads();
    cur ^= 1;
  }
}

// ---------------- K4: readout out[b][t][o] = hs . Wfc^T + b_fc ----------------
__launch_bounds__(256, 2)
__global__ void k_fc(const half_t* __restrict__ hs, const u32* __restrict__ Wfc_pk,
                     const float* __restrict__ b_fc, float* __restrict__ out) {
  const int l = threadIdx.x;
  const int w = l >> 6;                       // wave 0..3
  const int o = (l & 31) + w * 32;
  const int kh = (l >> 5) & 1;                // k half
  const int r0 = blockIdx.x * 256;
  __shared__ u32 sb[2][256];
  u32 W[128];
#pragma unroll
  for (int i = 0; i < 32; ++i)
    *(uint4*)&W[i * 4] = *(const uint4*)(Wfc_pk + o * 256 + kh * 128 + i * 4);
  const float bf = b_fc[o];
  const u32* hsw = (const u32*)hs;

  u32 gA = hsw[(size_t)r0 * 256 + l];
  sb[0][l] = gA;
  gA = hsw[(size_t)(r0 + 1) * 256 + l];
  __syncthreads();
  for (int i = 0; i < 256; ++i) {
    if (i + 1 < 256) {
      sb[(i + 1) & 1][l] = gA;
      int nf = (i + 2 < 256) ? i + 2 : i + 1;
      gA = hsw[(size_t)(r0 + nf) * 256 + l];
    }
    float a0 = 0.f, a1 = 0.f;
#pragma unroll
    for (int m = 0; m < 32; ++m) {
      uint4 hv = *(const uint4*)&sb[i & 1][kh * 128 + m * 4];
      a0 = dot2w(W[m * 4 + 0], hv.x, a0);
      a1 = dot2w(W[m * 4 + 1], hv.y, a1);
      a0 = dot2w(W[m * 4 + 2], hv.z, a0);
      a1 = dot2w(W[m * 4 + 3], hv.w, a1);
    }
    float a = a0 + a1;
    a += __shfl_xor(a, 32, 64);
    if (kh == 0) out[(size_t)(r0 + i) * 128 + o] = a + bf;
    __syncthreads();
  }
}

extern "C" void kernel_launch(void* const* d_in, const int* in_sizes, int n_in,
                              void* d_out, int out_size, void* d_ws, size_t ws_size,
                              hipStream_t stream) {
  const float* x   = (const float*)d_in[0];
  const float* h0  = (const float*)d_in[1];
  const float* Wih = (const float*)d_in[2];
  const float* bih = (const float*)d_in[3];
  const float* Whh = (const float*)d_in[4];
  const float* bhh = (const float*)d_in[5];
  const float* Mih = (const float*)d_in[6];
  const float* Mhh = (const float*)d_in[7];
  const float* Wfc = (const float*)d_in[8];
  const float* bfc = (const float*)d_in[9];
  float* out = (float*)d_out;

  char* ws = (char*)d_ws;
  // layout (total ~128.8 MB):
  //   xproj/hs shared fp16 buffer (128 MB) | Whh_pk (512KB) | Wih_pk (128KB) | Wfc_pk (128KB)
  half_t* xproj = (half_t*)(ws);                         // aliased: becomes hs after k_rec
  u32* Whh_pk = (u32*)(ws + 134217728);
  u32* Wih_pk = (u32*)(ws + 134217728 + 524288);
  u32* Wfc_pk = (u32*)(ws + 134217728 + 524288 + 131072);

  hipLaunchKernelGGL(k_prep, dim3(768), dim3(256), 0, stream,
                     Whh, Mhh, Wih, Mih, Wfc, Whh_pk, Wih_pk, Wfc_pk);
  hipLaunchKernelGGL(k_xproj, dim3(512), dim3(512), 0, stream,
                     x, Wih_pk, bih, bhh, xproj);
  hipLaunchKernelGGL(k_rec, dim3(64), dim3(512), 0, stream,
                     Whh_pk, xproj, h0);
  hipLaunchKernelGGL(k_fc, dim3(512), dim3(256), 0, stream,
                     xproj, Wfc_pk, bfc, out);
}

// Round 4
// 4899.484 us; speedup vs baseline: 1.0218x; 1.0218x over previous
//
#include <hip/hip_runtime.h>

typedef unsigned int u32;
typedef _Float16 half_t;
typedef _Float16 half2_t __attribute__((ext_vector_type(2)));

#define B_ 64
#define T_ 2048
#define I_ 128
#define H_ 512
#define O_ 128

static __device__ __forceinline__ float dot2w(u32 w, u32 h, float acc) {
  return __builtin_amdgcn_fdot2(__builtin_bit_cast(half2_t, w),
                                __builtin_bit_cast(half2_t, h), acc, false);
}

// ---------------- K1: pack masked weights to fp16 layouts ----------------
// Whh_pk layout: word q (=j*32+m) of lane l stored at [ (q/4)*2048 + l*4 + (q&3) ]
//   lane l owns rows r_j = (l>>3)*8 + j (j=0..7), k-range [ (l&7)*64, +64 )
__global__ void k_prep(const float* __restrict__ Whh, const float* __restrict__ Mhh,
                       const float* __restrict__ Wih, const float* __restrict__ Mih,
                       const float* __restrict__ Wfc,
                       u32* __restrict__ Whh_pk, u32* __restrict__ Wih_pk,
                       u32* __restrict__ Wfc_pk) {
  int idx = blockIdx.x * 256 + threadIdx.x;
  if (idx < 512 * 256) {
    int w4 = idx >> 11;
    int rem = idx & 2047;
    int l = rem >> 2;
    int c = rem & 3;
    int q = w4 * 4 + c;
    int j = q >> 5;
    int m = q & 31;
    int row = (l >> 3) * 8 + j;
    int k0 = (l & 7) * 64 + m * 2;
    float a = Whh[row * 512 + k0]     * Mhh[row * 512 + k0];
    float b = Whh[row * 512 + k0 + 1] * Mhh[row * 512 + k0 + 1];
    half2_t hv = { (half_t)a, (half_t)b };
    Whh_pk[idx] = __builtin_bit_cast(u32, hv);
  } else if (idx < 512 * 256 + 512 * 64) {
    int i2 = idx - 512 * 256;
    int h = i2 >> 6, w = i2 & 63;
    int k0 = w * 2;
    float a = Wih[h * 128 + k0]     * Mih[h * 128 + k0];
    float b = Wih[h * 128 + k0 + 1] * Mih[h * 128 + k0 + 1];
    half2_t hv = { (half_t)a, (half_t)b };
    Wih_pk[h * 64 + w] = __builtin_bit_cast(u32, hv);
  } else if (idx < 512 * 256 + 512 * 64 + 128 * 256) {
    int i3 = idx - (512 * 256 + 512 * 64);
    int o = i3 >> 8, w = i3 & 255;
    float a = Wfc[o * 512 + 2 * w];
    float b = Wfc[o * 512 + 2 * w + 1];
    half2_t hv = { (half_t)a, (half_t)b };
    Wfc_pk[o * 256 + w] = __builtin_bit_cast(u32, hv);
  }
}

// ---------------- K2: xproj[b][t][h] = x . Wih_m^T + b_ih + b_hh (fp16 out) ----
__launch_bounds__(512, 2)
__global__ void k_xproj(const float* __restrict__ x, const u32* __restrict__ Wih_pk,
                        const float* __restrict__ b_ih, const float* __restrict__ b_hh,
                        half_t* __restrict__ xp) {
  const int l = threadIdx.x;           // l = h
  const int r0 = blockIdx.x * 256;     // 256 (b,t) rows per block
  __shared__ u32 xb[2][64];
  u32 W[64];
#pragma unroll
  for (int i = 0; i < 16; ++i)
    *(uint4*)&W[i * 4] = *(const uint4*)(Wih_pk + l * 64 + i * 4);
  const float bs = b_ih[l] + b_hh[l];

  float2 g = { 0.f, 0.f };
  if (l < 64) {
    g = *(const float2*)(x + (size_t)r0 * 128 + 2 * l);
    half2_t hv = { (half_t)g.x, (half_t)g.y };
    xb[0][l] = __builtin_bit_cast(u32, hv);
    g = *(const float2*)(x + (size_t)(r0 + 1) * 128 + 2 * l);
  }
  __syncthreads();
  for (int i = 0; i < 256; ++i) {
    if (l < 64 && i + 1 < 256) {
      half2_t hv = { (half_t)g.x, (half_t)g.y };
      xb[(i + 1) & 1][l] = __builtin_bit_cast(u32, hv);
      int nf = (i + 2 < 256) ? i + 2 : i + 1;
      g = *(const float2*)(x + (size_t)(r0 + nf) * 128 + 2 * l);
    }
    float a0 = 0.f, a1 = 0.f;
#pragma unroll
    for (int m = 0; m < 16; ++m) {
      uint4 hv = *(const uint4*)&xb[i & 1][m * 4];
      a0 = dot2w(W[m * 4 + 0], hv.x, a0);
      a1 = dot2w(W[m * 4 + 1], hv.y, a1);
      a0 = dot2w(W[m * 4 + 2], hv.z, a0);
      a1 = dot2w(W[m * 4 + 3], hv.w, a1);
    }
    xp[(size_t)(r0 + i) * 512 + l] = (half_t)(a0 + a1 + bs);
    __syncthreads();
  }
}

// ---------------- K3: recurrence, one block per batch element ----------------
// hs aliases xp (read-before-write per t with 2-deep prefetch; disjoint b per block).
// Weights: 160 u32/lane FORCED VGPR-resident via asm launder (defeats the
// compiler's rematerialization of const-__restrict__ loads back into the loop,
// which is what produced VGPR_Count=128 + full L2 re-streaming in r2/r3).
// m4 groups 5..7 (96 u32/lane = 96 KB/CU/step) streamed from L2 each step.
__launch_bounds__(512, 2)
__global__ void k_rec(const u32* __restrict__ Whh_pk, half_t* __restrict__ xp,
                      const float* __restrict__ h0) {
  const int b = blockIdx.x;
  const int l = threadIdx.x;
  const int g = l & 7;                  // k-group: k in [g*64, g*64+64)

  __shared__ u32 hbuf[2][288];          // h fp16 packed; 32-word chunks padded +4

  // register-resident weights: m4 groups 0..4 -> W[j*20 + m4*4 + i]
  u32 W[160];
#pragma unroll
  for (int j = 0; j < 8; ++j)
#pragma unroll
    for (int m4 = 0; m4 < 5; ++m4) {
      uint4 v = *(const uint4*)(Whh_pk + (size_t)(j * 8 + m4) * 2048 + l * 4);
      W[j * 20 + m4 * 4 + 0] = v.x; W[j * 20 + m4 * 4 + 1] = v.y;
      W[j * 20 + m4 * 4 + 2] = v.z; W[j * 20 + m4 * 4 + 3] = v.w;
    }
  // force true residency: opaque asm pins each value in a VGPR; no remat possible
#pragma unroll
  for (int i = 0; i < 160; ++i) asm volatile("" : "+v"(W[i]));

  // initial h from h0 (padded-chunk layout: word w goes to w + (w/32)*4)
  if (l < 256) {
    float2 hv = *(const float2*)(h0 + (size_t)b * 512 + 2 * l);
    half2_t hh = { (half_t)hv.x, (half_t)hv.y };
    hbuf[0][l + (l >> 5) * 4] = __builtin_bit_cast(u32, hh);
  }
  __syncthreads();

  const uint4* wstream = (const uint4*)Whh_pk + l;   // element (j*8+m4)*512

  half_t* xpb = xp + (size_t)b * T_ * 512 + l;       // row == l
  half_t xp0 = xpb[0];
  half_t xp1 = xpb[512];

  const int b0 = l & 1, b1 = (l >> 1) & 1, b2 = (l >> 2) & 1;
  const int hwIdx = (l >> 1) + (l >> 6) * 4;         // padded word idx of row's halfword
  int cur = 0;

  for (int t = 0; t < T_; ++t) {
    // ---- issue streamed batches m4=5,6 early (latency hides under reg dots) ----
    const uint4* p5 = wstream;
    asm volatile("" : "+v"(p5));
    uint4 L5[8];
#pragma unroll
    for (int j = 0; j < 8; ++j) L5[j] = p5[(j * 8 + 5) * 512];

    const uint4* p6 = wstream;
    asm volatile("" : "+v"(p6));
    uint4 L6[8];
#pragma unroll
    for (int j = 0; j < 8; ++j) L6[j] = p6[(j * 8 + 6) * 512];

    int tpf = (t + 2 < T_) ? t + 2 : T_ - 1;
    half_t xpn = xpb[(size_t)tpf * 512];             // xp prefetch, 2 steps ahead

    float acc[8];
#pragma unroll
    for (int j = 0; j < 8; ++j) acc[j] = 0.f;

    // ---- m4 = 0..4 from registers (~320 cyc: covers b5/b6 L2 latency) ----
#pragma unroll
    for (int m4 = 0; m4 < 5; ++m4) {
      uint4 hh = *(const uint4*)&hbuf[cur][g * 36 + m4 * 4];
#pragma unroll
      for (int j = 0; j < 8; ++j) {
        acc[j] = dot2w(W[j * 20 + m4 * 4 + 0], hh.x, acc[j]);
        acc[j] = dot2w(W[j * 20 + m4 * 4 + 1], hh.y, acc[j]);
        acc[j] = dot2w(W[j * 20 + m4 * 4 + 2], hh.z, acc[j]);
        acc[j] = dot2w(W[j * 20 + m4 * 4 + 3], hh.w, acc[j]);
      }
    }

    // ---- consume b5 (frees its 32 regs), then issue b7 into them ----
    {
      uint4 hh = *(const uint4*)&hbuf[cur][g * 36 + 20];
#pragma unroll
      for (int j = 0; j < 8; ++j) {
        acc[j] = dot2w(L5[j].x, hh.x, acc[j]);
        acc[j] = dot2w(L5[j].y, hh.y, acc[j]);
        acc[j] = dot2w(L5[j].z, hh.z, acc[j]);
        acc[j] = dot2w(L5[j].w, hh.w, acc[j]);
      }
    }
    const uint4* p7 = wstream;
    asm volatile("" : "+v"(p7));
    uint4 L7[8];
#pragma unroll
    for (int j = 0; j < 8; ++j) L7[j] = p7[(j * 8 + 7) * 512];

    // ---- consume b6, then b7 ----
    {
      uint4 hh = *(const uint4*)&hbuf[cur][g * 36 + 24];
#pragma unroll
      for (int j = 0; j < 8; ++j) {
        acc[j] = dot2w(L6[j].x, hh.x, acc[j]);
        acc[j] = dot2w(L6[j].y, hh.y, acc[j]);
        acc[j] = dot2w(L6[j].z, hh.z, acc[j]);
        acc[j] = dot2w(L6[j].w, hh.w, acc[j]);
      }
    }
    {
      uint4 hh = *(const uint4*)&hbuf[cur][g * 36 + 28];
#pragma unroll
      for (int j = 0; j < 8; ++j) {
        acc[j] = dot2w(L7[j].x, hh.x, acc[j]);
        acc[j] = dot2w(L7[j].y, hh.y, acc[j]);
        acc[j] = dot2w(L7[j].z, hh.z, acc[j]);
        acc[j] = dot2w(L7[j].w, hh.w, acc[j]);
      }
    }

    // keep-half butterfly over the 8-lane k-group dim; lane l ends with row l total
    float s4[4];
#pragma unroll
    for (int m = 0; m < 4; ++m) {
      float keep = b0 ? acc[2 * m + 1] : acc[2 * m];
      float send = b0 ? acc[2 * m]     : acc[2 * m + 1];
      s4[m] = keep + __shfl_xor(send, 1, 64);
    }
    float s2[2];
#pragma unroll
    for (int m = 0; m < 2; ++m) {
      float keep = b1 ? s4[2 * m + 1] : s4[2 * m];
      float send = b1 ? s4[2 * m]     : s4[2 * m + 1];
      s2[m] = keep + __shfl_xor(send, 2, 64);
    }
    float keepf = b2 ? s2[1] : s2[0];
    float sendf = b2 ? s2[0] : s2[1];
    float tot = keepf + __shfl_xor(sendf, 4, 64);

    float sarg = tot + (float)xp0;
    float ax = fabsf(sarg);
    float e = __expf(-2.f * ax);
    float r = (1.f - e) * __builtin_amdgcn_rcpf(1.f + e);
    float hval = copysignf(r, sarg);

    half_t hv = (half_t)hval;
    ((half_t*)hbuf[cur ^ 1])[hwIdx * 2 + (l & 1)] = hv;
    xpb[(size_t)t * 512] = hv;            // overwrite consumed xproj slot with h

    xp0 = xp1; xp1 = xpn;
    __syncthreads();
    cur ^= 1;
  }
}

// ---------------- K4: readout out[b][t][o] = hs . Wfc^T + b_fc ----------------
__launch_bounds__(256, 2)
__global__ void k_fc(const half_t* __restrict__ hs, const u32* __restrict__ Wfc_pk,
                     const float* __restrict__ b_fc, float* __restrict__ out) {
  const int l = threadIdx.x;
  const int w = l >> 6;                       // wave 0..3
  const int o = (l & 31) + w * 32;
  const int kh = (l >> 5) & 1;                // k half
  const int r0 = blockIdx.x * 256;
  __shared__ u32 sb[2][256];
  u32 W[128];
#pragma unroll
  for (int i = 0; i < 32; ++i)
    *(uint4*)&W[i * 4] = *(const uint4*)(Wfc_pk + o * 256 + kh * 128 + i * 4);
  const float bf = b_fc[o];
  const u32* hsw = (const u32*)hs;

  u32 gA = hsw[(size_t)r0 * 256 + l];
  sb[0][l] = gA;
  gA = hsw[(size_t)(r0 + 1) * 256 + l];
  __syncthreads();
  for (int i = 0; i < 256; ++i) {
    if (i + 1 < 256) {
      sb[(i + 1) & 1][l] = gA;
      int nf = (i + 2 < 256) ? i + 2 : i + 1;
      gA = hsw[(size_t)(r0 + nf) * 256 + l];
    }
    float a0 = 0.f, a1 = 0.f;
#pragma unroll
    for (int m = 0; m < 32; ++m) {
      uint4 hv = *(const uint4*)&sb[i & 1][kh * 128 + m * 4];
      a0 = dot2w(W[m * 4 + 0], hv.x, a0);
      a1 = dot2w(W[m * 4 + 1], hv.y, a1);
      a0 = dot2w(W[m * 4 + 2], hv.z, a0);
      a1 = dot2w(W[m * 4 + 3], hv.w, a1);
    }
    float a = a0 + a1;
    a += __shfl_xor(a, 32, 64);
    if (kh == 0) out[(size_t)(r0 + i) * 128 + o] = a + bf;
    __syncthreads();
  }
}

extern "C" void kernel_launch(void* const* d_in, const int* in_sizes, int n_in,
                              void* d_out, int out_size, void* d_ws, size_t ws_size,
                              hipStream_t stream) {
  const float* x   = (const float*)d_in[0];
  const float* h0  = (const float*)d_in[1];
  const float* Wih = (const float*)d_in[2];
  const float* bih = (const float*)d_in[3];
  const float* Whh = (const float*)d_in[4];
  const float* bhh = (const float*)d_in[5];
  const float* Mih = (const float*)d_in[6];
  const float* Mhh = (const float*)d_in[7];
  const float* Wfc = (const float*)d_in[8];
  const float* bfc = (const float*)d_in[9];
  float* out = (float*)d_out;

  char* ws = (char*)d_ws;
  // layout (total ~128.8 MB):
  //   xproj/hs shared fp16 buffer (128 MB) | Whh_pk (512KB) | Wih_pk (128KB) | Wfc_pk (128KB)
  half_t* xproj = (half_t*)(ws);                         // aliased: becomes hs after k_rec
  u32* Whh_pk = (u32*)(ws + 134217728);
  u32* Wih_pk = (u32*)(ws + 134217728 + 524288);
  u32* Wfc_pk = (u32*)(ws + 134217728 + 524288 + 131072);

  hipLaunchKernelGGL(k_prep, dim3(768), dim3(256), 0, stream,
                     Whh, Mhh, Wih, Mih, Wfc, Whh_pk, Wih_pk, Wfc_pk);
  hipLaunchKernelGGL(k_xproj, dim3(512), dim3(512), 0, stream,
                     x, Wih_pk, bih, bhh, xproj);
  hipLaunchKernelGGL(k_rec, dim3(64), dim3(512), 0, stream,
                     Whh_pk, xproj, h0);
  hipLaunchKernelGGL(k_fc, dim3(512), dim3(256), 0, stream,
                     xproj, Wfc_pk, bfc, out);
}

// Round 6
// 4612.779 us; speedup vs baseline: 1.0853x; 1.0622x over previous
//
#include <hip/hip_runtime.h>

typedef unsigned int u32;
typedef _Float16 half_t;
typedef _Float16 half2_t __attribute__((ext_vector_type(2)));

#define B_ 64
#define T_ 2048
#define I_ 128
#define H_ 512
#define O_ 128

static __device__ __forceinline__ float dot2w(u32 w, u32 h, float acc) {
  return __builtin_amdgcn_fdot2(__builtin_bit_cast(half2_t, w),
                                __builtin_bit_cast(half2_t, h), acc, false);
}

// ---------------- K1: pack masked weights to fp16 layouts ----------------
// Whh_pk layout: word q (=j*32+m) of lane l stored at [ (q/4)*2048 + l*4 + (q&3) ]
//   lane l owns rows r_j = (l>>3)*8 + j (j=0..7), k-range [ (l&7)*64, +64 )
__global__ void k_prep(const float* __restrict__ Whh, const float* __restrict__ Mhh,
                       const float* __restrict__ Wih, const float* __restrict__ Mih,
                       const float* __restrict__ Wfc,
                       u32* __restrict__ Whh_pk, u32* __restrict__ Wih_pk,
                       u32* __restrict__ Wfc_pk) {
  int idx = blockIdx.x * 256 + threadIdx.x;
  if (idx < 512 * 256) {
    int w4 = idx >> 11;
    int rem = idx & 2047;
    int l = rem >> 2;
    int c = rem & 3;
    int q = w4 * 4 + c;
    int j = q >> 5;
    int m = q & 31;
    int row = (l >> 3) * 8 + j;
    int k0 = (l & 7) * 64 + m * 2;
    float a = Whh[row * 512 + k0]     * Mhh[row * 512 + k0];
    float b = Whh[row * 512 + k0 + 1] * Mhh[row * 512 + k0 + 1];
    half2_t hv = { (half_t)a, (half_t)b };
    Whh_pk[idx] = __builtin_bit_cast(u32, hv);
  } else if (idx < 512 * 256 + 512 * 64) {
    int i2 = idx - 512 * 256;
    int h = i2 >> 6, w = i2 & 63;
    int k0 = w * 2;
    float a = Wih[h * 128 + k0]     * Mih[h * 128 + k0];
    float b = Wih[h * 128 + k0 + 1] * Mih[h * 128 + k0 + 1];
    half2_t hv = { (half_t)a, (half_t)b };
    Wih_pk[h * 64 + w] = __builtin_bit_cast(u32, hv);
  } else if (idx < 512 * 256 + 512 * 64 + 128 * 256) {
    int i3 = idx - (512 * 256 + 512 * 64);
    int o = i3 >> 8, w = i3 & 255;
    float a = Wfc[o * 512 + 2 * w];
    float b = Wfc[o * 512 + 2 * w + 1];
    half2_t hv = { (half_t)a, (half_t)b };
    Wfc_pk[o * 256 + w] = __builtin_bit_cast(u32, hv);
  }
}

// ---------------- K2: xproj[b][t][h] = x . Wih_m^T + b_ih + b_hh (fp16 out) ----
__launch_bounds__(512, 2)
__global__ void k_xproj(const float* __restrict__ x, const u32* __restrict__ Wih_pk,
                        const float* __restrict__ b_ih, const float* __restrict__ b_hh,
                        half_t* __restrict__ xp) {
  const int l = threadIdx.x;           // l = h
  const int r0 = blockIdx.x * 256;     // 256 (b,t) rows per block
  __shared__ u32 xb[2][64];
  u32 W[64];
#pragma unroll
  for (int i = 0; i < 16; ++i)
    *(uint4*)&W[i * 4] = *(const uint4*)(Wih_pk + l * 64 + i * 4);
  const float bs = b_ih[l] + b_hh[l];

  float2 g = { 0.f, 0.f };
  if (l < 64) {
    g = *(const float2*)(x + (size_t)r0 * 128 + 2 * l);
    half2_t hv = { (half_t)g.x, (half_t)g.y };
    xb[0][l] = __builtin_bit_cast(u32, hv);
    g = *(const float2*)(x + (size_t)(r0 + 1) * 128 + 2 * l);
  }
  __syncthreads();
  for (int i = 0; i < 256; ++i) {
    if (l < 64 && i + 1 < 256) {
      half2_t hv = { (half_t)g.x, (half_t)g.y };
      xb[(i + 1) & 1][l] = __builtin_bit_cast(u32, hv);
      int nf = (i + 2 < 256) ? i + 2 : i + 1;
      g = *(const float2*)(x + (size_t)(r0 + nf) * 128 + 2 * l);
    }
    float a0 = 0.f, a1 = 0.f;
#pragma unroll
    for (int m = 0; m < 16; ++m) {
      uint4 hv = *(const uint4*)&xb[i & 1][m * 4];
      a0 = dot2w(W[m * 4 + 0], hv.x, a0);
      a1 = dot2w(W[m * 4 + 1], hv.y, a1);
      a0 = dot2w(W[m * 4 + 2], hv.z, a0);
      a1 = dot2w(W[m * 4 + 3], hv.w, a1);
    }
    xp[(size_t)(r0 + i) * 512 + l] = (half_t)(a0 + a1 + bs);
    __syncthreads();
  }
}

// ---------------- K3: recurrence, one block per batch element ----------------
// hs aliases xp (read-before-write per t with 2-deep prefetch; disjoint b per block).
// Weights: 45 frags/lane (180 u32) as NAMED u32 SSA scalars, laundered
// COMPONENT-WISE ("+v" on u32 — 128-bit tied operands don't compile, r5) ->
// true VGPR residency: no alloca (rule #20), no remat (opaque origin).
// Remaining 19 frags/lane re-streamed from L2 each step (~155 KB/CU/step at
// ~117 B/cyc TA/L2 ingest), software-pipelined 2 m4-groups ahead, per-group
// 64-bit pointer launder (verified constraint) blocks cross-iteration CSE.
#define WPLD(N, J, M4) u32 N##_x, N##_y, N##_z, N##_w; \
  { uint4 t_ = wpk4[((J) * 8 + (M4)) * 512 + l]; \
    N##_x = t_.x; N##_y = t_.y; N##_z = t_.z; N##_w = t_.w; }
#define DECLROW(J) WPLD(W##J##_0, J, 0) WPLD(W##J##_1, J, 1) WPLD(W##J##_2, J, 2) \
                   WPLD(W##J##_3, J, 3) WPLD(W##J##_4, J, 4) WPLD(W##J##_5, J, 5) \
                   WPLD(W##J##_6, J, 6) WPLD(W##J##_7, J, 7)
#define LNDF(N) asm volatile("" : "+v"(N##_x), "+v"(N##_y), "+v"(N##_z), "+v"(N##_w));
#define LNDROW(J) LNDF(W##J##_0) LNDF(W##J##_1) LNDF(W##J##_2) LNDF(W##J##_3) \
                  LNDF(W##J##_4) LNDF(W##J##_5) LNDF(W##J##_6) LNDF(W##J##_7)
#define DOTR(Jn, N) { acc[Jn] = dot2w(N##_x, hh.x, acc[Jn]); acc[Jn] = dot2w(N##_y, hh.y, acc[Jn]); \
                      acc[Jn] = dot2w(N##_z, hh.z, acc[Jn]); acc[Jn] = dot2w(N##_w, hh.w, acc[Jn]); }
#define DOTU(Jn, V) { acc[Jn] = dot2w((V).x, hh.x, acc[Jn]); acc[Jn] = dot2w((V).y, hh.y, acc[Jn]); \
                      acc[Jn] = dot2w((V).z, hh.z, acc[Jn]); acc[Jn] = dot2w((V).w, hh.w, acc[Jn]); }
#define ISS2(M) const uint4* p##M = wst; asm volatile("" : "+v"(p##M)); \
  uint4 s6_##M = p##M[(48 + M) * 512]; uint4 s7_##M = p##M[(56 + M) * 512];
#define ISS3(M) const uint4* p##M = wst; asm volatile("" : "+v"(p##M)); \
  uint4 s5_##M = p##M[(40 + M) * 512]; uint4 s6_##M = p##M[(48 + M) * 512]; \
  uint4 s7_##M = p##M[(56 + M) * 512];
#define BLK_A(M) { uint4 hh = *(const uint4*)&hbc[g * 36 + M * 4]; \
  DOTR(0, W0_##M) DOTR(1, W1_##M) DOTR(2, W2_##M) DOTR(3, W3_##M) DOTR(4, W4_##M) \
  DOTR(5, W5_##M) DOTU(6, s6_##M) DOTU(7, s7_##M) }
#define BLK_B(M) { uint4 hh = *(const uint4*)&hbc[g * 36 + M * 4]; \
  DOTR(0, W0_##M) DOTR(1, W1_##M) DOTR(2, W2_##M) DOTR(3, W3_##M) DOTR(4, W4_##M) \
  DOTU(5, s5_##M) DOTU(6, s6_##M) DOTU(7, s7_##M) }

__launch_bounds__(512, 1)
__global__ void k_rec(const u32* __restrict__ Whh_pk, half_t* __restrict__ xp,
                      const float* __restrict__ h0) {
  const int b = blockIdx.x;
  const int l = threadIdx.x;
  const int g = l & 7;                  // k-group: k in [g*64, g*64+64)

  __shared__ u32 hbuf[2][288];          // h fp16 packed; 32-word chunks padded +4

  const uint4* wpk4 = (const uint4*)Whh_pk;

  // 45 register-resident frags: rows 0..4 all m4 (40) + row 5 m4 0..4 (5)
  DECLROW(0) DECLROW(1) DECLROW(2) DECLROW(3) DECLROW(4)
  WPLD(W5_0, 5, 0) WPLD(W5_1, 5, 1) WPLD(W5_2, 5, 2) WPLD(W5_3, 5, 3) WPLD(W5_4, 5, 4)

  // pin as opaque register values (no remat, no alloca)
  LNDROW(0) LNDROW(1) LNDROW(2) LNDROW(3) LNDROW(4)
  LNDF(W5_0) LNDF(W5_1) LNDF(W5_2) LNDF(W5_3) LNDF(W5_4)

  // initial h from h0 (padded-chunk layout: word w goes to w + (w/32)*4)
  if (l < 256) {
    float2 hv = *(const float2*)(h0 + (size_t)b * 512 + 2 * l);
    half2_t hh = { (half_t)hv.x, (half_t)hv.y };
    hbuf[0][l + (l >> 5) * 4] = __builtin_bit_cast(u32, hh);
  }
  __syncthreads();

  const uint4* wst = wpk4 + l;                       // streamed-frag base, per lane

  half_t* xpb = xp + (size_t)b * T_ * 512 + l;       // row == l
  half_t xp0 = xpb[0];
  half_t xp1 = xpb[512];

  const int b0 = l & 1, b1 = (l >> 1) & 1, b2 = (l >> 2) & 1;
  const int hwIdx = (l >> 1) + (l >> 6) * 4;         // padded word idx of row's halfword
  int cur = 0;

  for (int t = 0; t < T_; ++t) {
    const u32* hbc = hbuf[cur];

    ISS2(0) ISS2(1)                                  // prologue: 2 groups in flight

    int tpf = (t + 2 < T_) ? t + 2 : T_ - 1;
    half_t xpn = xpb[(size_t)tpf * 512];             // xp prefetch, 2 steps ahead

    float acc[8];
#pragma unroll
    for (int j = 0; j < 8; ++j) acc[j] = 0.f;

    BLK_A(0) ISS2(2)
    BLK_A(1) ISS2(3)
    BLK_A(2) ISS2(4)
    BLK_A(3) ISS3(5)
    BLK_A(4) ISS3(6)
    BLK_B(5) ISS3(7)
    BLK_B(6)
    BLK_B(7)

    // keep-half butterfly over the 8-lane k-group dim; lane l ends with row l total
    float s4[4];
#pragma unroll
    for (int m = 0; m < 4; ++m) {
      float keep = b0 ? acc[2 * m + 1] : acc[2 * m];
      float send = b0 ? acc[2 * m]     : acc[2 * m + 1];
      s4[m] = keep + __shfl_xor(send, 1, 64);
    }
    float s2[2];
#pragma unroll
    for (int m = 0; m < 2; ++m) {
      float keep = b1 ? s4[2 * m + 1] : s4[2 * m];
      float send = b1 ? s4[2 * m]     : s4[2 * m + 1];
      s2[m] = keep + __shfl_xor(send, 2, 64);
    }
    float keepf = b2 ? s2[1] : s2[0];
    float sendf = b2 ? s2[0] : s2[1];
    float tot = keepf + __shfl_xor(sendf, 4, 64);

    float sarg = tot + (float)xp0;
    float ax = fabsf(sarg);
    float e = __expf(-2.f * ax);
    float r = (1.f - e) * __builtin_amdgcn_rcpf(1.f + e);
    float hval = copysignf(r, sarg);

    half_t hv = (half_t)hval;
    ((half_t*)hbuf[cur ^ 1])[hwIdx * 2 + (l & 1)] = hv;
    xpb[(size_t)t * 512] = hv;            // overwrite consumed xproj slot with h

    xp0 = xp1; xp1 = xpn;
    __syncthreads();
    cur ^= 1;
  }
}

// ---------------- K4: readout out[b][t][o] = hs . Wfc^T + b_fc ----------------
__launch_bounds__(256, 2)
__global__ void k_fc(const half_t* __restrict__ hs, const u32* __restrict__ Wfc_pk,
                     const float* __restrict__ b_fc, float* __restrict__ out) {
  const int l = threadIdx.x;
  const int w = l >> 6;                       // wave 0..3
  const int o = (l & 31) + w * 32;
  const int kh = (l >> 5) & 1;                // k half
  const int r0 = blockIdx.x * 256;
  __shared__ u32 sb[2][256];
  u32 W[128];
#pragma unroll
  for (int i = 0; i < 32; ++i)
    *(uint4*)&W[i * 4] = *(const uint4*)(Wfc_pk + o * 256 + kh * 128 + i * 4);
  const float bf = b_fc[o];
  const u32* hsw = (const u32*)hs;

  u32 gA = hsw[(size_t)r0 * 256 + l];
  sb[0][l] = gA;
  gA = hsw[(size_t)(r0 + 1) * 256 + l];
  __syncthreads();
  for (int i = 0; i < 256; ++i) {
    if (i + 1 < 256) {
      sb[(i + 1) & 1][l] = gA;
      int nf = (i + 2 < 256) ? i + 2 : i + 1;
      gA = hsw[(size_t)(r0 + nf) * 256 + l];
    }
    float a0 = 0.f, a1 = 0.f;
#pragma unroll
    for (int m = 0; m < 32; ++m) {
      uint4 hv = *(const uint4*)&sb[i & 1][kh * 128 + m * 4];
      a0 = dot2w(W[m * 4 + 0], hv.x, a0);
      a1 = dot2w(W[m * 4 + 1], hv.y, a1);
      a0 = dot2w(W[m * 4 + 2], hv.z, a0);
      a1 = dot2w(W[m * 4 + 3], hv.w, a1);
    }
    float a = a0 + a1;
    a += __shfl_xor(a, 32, 64);
    if (kh == 0) out[(size_t)(r0 + i) * 128 + o] = a + bf;
    __syncthreads();
  }
}

extern "C" void kernel_launch(void* const* d_in, const int* in_sizes, int n_in,
                              void* d_out, int out_size, void* d_ws, size_t ws_size,
                              hipStream_t stream) {
  const float* x   = (const float*)d_in[0];
  const float* h0  = (const float*)d_in[1];
  const float* Wih = (const float*)d_in[2];
  const float* bih = (const float*)d_in[3];
  const float* Whh = (const float*)d_in[4];
  const float* bhh = (const float*)d_in[5];
  const float* Mih = (const float*)d_in[6];
  const float* Mhh = (const float*)d_in[7];
  const float* Wfc = (const float*)d_in[8];
  const float* bfc = (const float*)d_in[9];
  float* out = (float*)d_out;

  char* ws = (char*)d_ws;
  // layout (total ~128.8 MB):
  //   xproj/hs shared fp16 buffer (128 MB) | Whh_pk (512KB) | Wih_pk (128KB) | Wfc_pk (128KB)
  half_t* xproj = (half_t*)(ws);                         // aliased: becomes hs after k_rec
  u32* Whh_pk = (u32*)(ws + 134217728);
  u32* Wih_pk = (u32*)(ws + 134217728 + 524288);
  u32* Wfc_pk = (u32*)(ws + 134217728 + 524288 + 131072);

  hipLaunchKernelGGL(k_prep, dim3(768), dim3(256), 0, stream,
                     Whh, Mhh, Wih, Mih, Wfc, Whh_pk, Wih_pk, Wfc_pk);
  hipLaunchKernelGGL(k_xproj, dim3(512), dim3(512), 0, stream,
                     x, Wih_pk, bih, bhh, xproj);
  hipLaunchKernelGGL(k_rec, dim3(64), dim3(512), 0, stream,
                     Whh_pk, xproj, h0);
  hipLaunchKernelGGL(k_fc, dim3(512), dim3(256), 0, stream,
                     xproj, Wfc_pk, bfc, out);
}